// Round 12
// baseline (509.761 us; speedup 1.0000x reference)
//
#include <hip/hip_runtime.h>

constexpr int T = 168;
constexpr int P = 16;
constexpr int H = 24;

typedef float v2f __attribute__((ext_vector_type(2)));

__device__ __forceinline__ v2f mk2(float a, float b) { v2f r; r[0] = a; r[1] = b; return r; }
__device__ __forceinline__ v2f bc2(float a)          { v2f r; r[0] = a; r[1] = a; return r; }
// 2 fp32 FMAs in one instruction (v_pk_fma_f32).
__device__ __forceinline__ v2f pkfma(v2f a, v2f b, v2f c) {
    return __builtin_elementwise_fma(a, b, c);
}

__device__ __forceinline__ float rcp_f(float x) { return __builtin_amdgcn_rcpf(x); }
__device__ __forceinline__ float sigm_f(float x) { return rcp_f(1.f + __expf(-x)); }
// tanh(x) = 2*sigmoid(2x) - 1
__device__ __forceinline__ float tanh_fast(float x) {
    return fmaf(2.f, rcp_f(1.f + __expf(-2.f * x)), -1.f);
}

#define KEEP2(v) asm volatile("" : "+v"(v))
// Intra-wave LDS write->read ordering + compiler reorder fence.
#define LDS_SYNC() asm volatile("s_waitcnt lgkmcnt(0)" ::: "memory")

// 4 packed FMAs: acc += v4.{x,y,z,w} * w[b..b+3]
#define PK4(acc_, v4_, w_, b_) do {                       \
    acc_ = pkfma(bc2((v4_).x), (w_)[(b_)],     acc_);     \
    acc_ = pkfma(bc2((v4_).y), (w_)[(b_) + 1], acc_);     \
    acc_ = pkfma(bc2((v4_).z), (w_)[(b_) + 2], acc_);     \
    acc_ = pkfma(bc2((v4_).w), (w_)[(b_) + 3], acc_); } while (0)

// Gate nonlinearity + state update + h store. tdst==nullptr folds away.
__device__ __forceinline__ void act_store(v2f g, int lane, int half,
                                          float& c, float* hdst, float* tdst)
{
    float a0 = sigm_f(g[0]);                        // i (half0) | f (half1)
    float px = (half == 0) ? g[1] + g[1] : g[1];
    float sv = sigm_f(px);
    float a1 = (half == 0) ? sv + sv - 1.f : sv;    // tanh(g) | o
    float fa = __shfl(a0, lane + 24);
    float oa = __shfl(a1, lane + 24);
    c = fmaf(fa, c, a0 * a1);
    float hv = oa * tanh_fast(c);
    if (tdst) {
        float th = tanh_fast(hv);
        if (lane < H) { hdst[lane] = hv; tdst[lane] = th; }
    } else {
        if (lane < H) hdst[lane] = hv;
    }
}

// x-part: acc += Wih*x (wave0, w[0..15]), 4 float4 of x
#define XPART(acc_, xrow_) do {                                        \
    const float4* x4_ = (const float4*)(xrow_);                        \
    _Pragma("unroll")                                                  \
    for (int j_ = 0; j_ < P / 4; ++j_) {                               \
        float4 v_ = x4_[j_];                                           \
        PK4(acc_, v_, w, 4 * j_);                                      \
    }                                                                  \
} while (0)

// t-part: acc += Wih2*t1 (wave1, w[0..23]), 6 float4 from LDS
#define TPART(acc_, trow_) do {                                        \
    _Pragma("unroll")                                                  \
    for (int k_ = 0; k_ < H / 4; ++k_) {                               \
        float4 tv_ = ((const float4*)(trow_))[k_];                     \
        PK4(acc_, tv_, w, 4 * k_);                                     \
    }                                                                  \
} while (0)

// h-part: acc += Whh*h (both waves, w[24..47]), 6 float4 from LDS
#define HPART(acc_, hrow_) do {                                        \
    _Pragma("unroll")                                                  \
    for (int k_ = 0; k_ < H / 4; ++k_) {                               \
        float4 hv_ = ((const float4*)(hrow_))[k_];                     \
        PK4(acc_, hv_, w, H + 4 * k_);                                 \
    }                                                                  \
} while (0)

// R16 (resubmit after infra failure): cross-step software pipelining INSIDE
// the superstep.
// Evidence: R15 (84 barriers) == R14 (167 barriers) == ~335us steady — the
// fixed-cost theory is null. Residual ~37% no-issue = the serial per-step
// chain (ds_read h ~120cy -> 24-deep FMA -> exp/rcp -> 2x bpermute ~60cy ->
// tanh -> ds_write -> drain) with only 2 independent row chains to cover it.
// Change: within each superstep, BOTH steps' input-part gate accumulations
// (wave0: Wih1*x[t],x[t+1]; wave1: Wih2*t1 for both sub-steps — all inputs
// available at superstep start) hoist to the top: 32-48 independent pkfma +
// their loads now sink into step-t's act-chain stalls. Costs 2 extra live
// v2f accs (4 regs); peak ~112-126 unified — inside the proven 128 alloc.
// Keeps: R15 superstep/barrier structure, wave0=L1/wave1=L2 split, t1
// double-buffer, uniform init, amdgpu_num_vgpr(128), 2048 blocks x 2 waves.
__global__ __attribute__((amdgpu_flat_work_group_size(128, 128),
                          amdgpu_num_vgpr(128)))
void lstm2_split5(const float* __restrict__ x,
                  const float* __restrict__ Wih1, const float* __restrict__ Whh1,
                  const float* __restrict__ bih1, const float* __restrict__ bhh1,
                  const float* __restrict__ Wih2, const float* __restrict__ Whh2,
                  const float* __restrict__ bih2, const float* __restrict__ bhh2,
                  const float* __restrict__ W1, const float* __restrict__ b1,
                  const float* __restrict__ W2, const float* __restrict__ b2,
                  float* __restrict__ out)
{
    const int tid  = threadIdx.x;
    const int wid  = tid >> 6;                    // 0: L1 wave, 1: L2 wave
    const int lane = tid & 63;
    const int s    = (lane < 48) ? lane : 47;     // clamp idle lanes
    const int u    = s % H;                       // unit 0..23
    const int half = s / H;                       // 0: {i,g}, 1: {f,o}
    const int q0   = half * H + u;                // i or f gate row
    const int q1   = (2 + half) * H + u;          // g or o gate row
    const int rowA = blockIdx.x * 2;
    const int rowB = rowA + 1;

    // ---- uniform weight init: 48 v2f = 96 regs, same mapping both waves ----
    // w[0..23]:  input-weight pairs {q0,q1} (cols >= nin zero-padded)
    // w[24..47]: recurrent pairs {q0,q1}
    const float* __restrict__ Wi = wid ? Wih2 : Wih1;
    const float* __restrict__ Wh = wid ? Whh2 : Whh1;
    const float* __restrict__ bi = wid ? bih2 : bih1;
    const float* __restrict__ bh = wid ? bhh2 : bhh1;
    const int nin = wid ? H : P;                  // 24 | 16 (wave-uniform)

    v2f w[48];
    #pragma unroll
    for (int k = 0; k < H; ++k)
        w[k] = (k < nin) ? mk2(Wi[q0 * nin + k], Wi[q1 * nin + k]) : bc2(0.f);
    #pragma unroll
    for (int k = 0; k < H; ++k)
        w[H + k] = mk2(Wh[q0 * H + k], Wh[q1 * H + k]);
    v2f bias = mk2(bi[q0] + bh[q0], bi[q1] + bh[q1]);

    #pragma unroll
    for (int k = 0; k < 48; ++k) KEEP2(w[k]);
    KEEP2(bias);

    __shared__ __align__(16) float h1s[2][32];          // L1 h (wave0-private)
    __shared__ __align__(16) float t1s[2][2][2][32];    // [buf][step][row]
    __shared__ __align__(16) float h2s[2][32];          // L2 h (wave1-private)

    const float* __restrict__ xA = x + (size_t)rowA * T * P;  // wave-uniform
    const float* __restrict__ xB = x + (size_t)rowB * T * P;

    float cA = 0.f, cB = 0.f;     // c1 (wave0) / c2 (wave1)

    // ---- superstep 0: wave0 = L1 steps {0,1}; wave1 zero-inits h2 ----
    if (wid == 0) {
        // steps 0 (h1=0: x-part only) and 1, with step-1 x-part hoisted
        v2f gA0 = bias, gB0 = bias, gA1 = bias, gB1 = bias;
        XPART(gA0, xA);
        XPART(gB0, xB);
        XPART(gA1, xA + P);
        XPART(gB1, xB + P);
        act_store(gA0, lane, half, cA, h1s[0], t1s[0][0][0]);
        act_store(gB0, lane, half, cB, h1s[1], t1s[0][0][1]);
        LDS_SYNC();                     // own h1 writes -> own reads
        HPART(gA1, h1s[0]);
        act_store(gA1, lane, half, cA, h1s[0], t1s[0][1][0]);
        HPART(gB1, h1s[1]);
        act_store(gB1, lane, half, cB, h1s[1], t1s[0][1][1]);
    } else {
        if (lane < H) { h2s[0][lane] = 0.f; h2s[1][lane] = 0.f; }
    }
    LDS_SYNC();
    __builtin_amdgcn_s_barrier();

    // ---- supersteps 1..83: wave0 = L1 {2s,2s+1}; wave1 = L2 {2s-2,2s-1} ----
    for (int ss = 1; ss < T / 2; ++ss) {
        if (wid == 0) {
            const int ta = 2 * ss;
            // hoisted input parts: 4 independent accumulation chains
            v2f gA0 = bias, gB0 = bias, gA1 = bias, gB1 = bias;
            XPART(gA0, xA + ta * P);
            XPART(gB0, xB + ta * P);
            XPART(gA1, xA + (ta + 1) * P);
            XPART(gB1, xB + (ta + 1) * P);
            // step ta: recurrent part + act
            HPART(gA0, h1s[0]);
            act_store(gA0, lane, half, cA, h1s[0], t1s[ss & 1][0][0]);
            HPART(gB0, h1s[1]);
            act_store(gB0, lane, half, cB, h1s[1], t1s[ss & 1][0][1]);
            LDS_SYNC();
            // step ta+1
            HPART(gA1, h1s[0]);
            act_store(gA1, lane, half, cA, h1s[0], t1s[ss & 1][1][0]);
            HPART(gB1, h1s[1]);
            act_store(gB1, lane, half, cB, h1s[1], t1s[ss & 1][1][1]);
        } else {
            const int pb = (ss - 1) & 1;
            // hoisted input parts: both sub-steps' t1 are already in LDS
            v2f fA0 = bias, fB0 = bias, fA1 = bias, fB1 = bias;
            TPART(fA0, t1s[pb][0][0]);
            TPART(fB0, t1s[pb][0][1]);
            TPART(fA1, t1s[pb][1][0]);
            TPART(fB1, t1s[pb][1][1]);
            // step 0: recurrent part + act
            HPART(fA0, h2s[0]);
            act_store(fA0, lane, half, cA, h2s[0], nullptr);
            HPART(fB0, h2s[1]);
            act_store(fB0, lane, half, cB, h2s[1], nullptr);
            LDS_SYNC();
            // step 1
            HPART(fA1, h2s[0]);
            act_store(fA1, lane, half, cA, h2s[0], nullptr);
            HPART(fB1, h2s[1]);
            act_store(fB1, lane, half, cB, h2s[1], nullptr);
        }
        LDS_SYNC();
        __builtin_amdgcn_s_barrier();
    }

    // ---- tail (wave1 only): L2 steps {166,167} from buf 1, then head ----
    if (wid == 1) {
        v2f fA0 = bias, fB0 = bias, fA1 = bias, fB1 = bias;
        TPART(fA0, t1s[1][0][0]);
        TPART(fB0, t1s[1][0][1]);
        TPART(fA1, t1s[1][1][0]);
        TPART(fB1, t1s[1][1][1]);
        HPART(fA0, h2s[0]);
        act_store(fA0, lane, half, cA, h2s[0], nullptr);
        HPART(fB0, h2s[1]);
        act_store(fB0, lane, half, cB, h2s[1], nullptr);
        LDS_SYNC();
        HPART(fA1, h2s[0]);
        act_store(fA1, lane, half, cA, h2s[0], nullptr);
        HPART(fB1, h2s[1]);
        act_store(fB1, lane, half, cB, h2s[1], nullptr);
        LDS_SYNC();

        // head: tanh -> fc1(16, relu) -> fc2(24), both rows (intra-wave)
        if (lane < H) {
            t1s[0][0][0][lane] = tanh_fast(h2s[0][lane]);
            t1s[0][0][1][lane] = tanh_fast(h2s[1][lane]);
        }
        LDS_SYNC();
        if (lane < 16) {
            float accA = b1[lane], accB = b1[lane];
            #pragma unroll
            for (int j = 0; j < H; ++j) {
                float wv = W1[lane * H + j];
                accA = fmaf(t1s[0][0][0][j], wv, accA);
                accB = fmaf(t1s[0][0][1][j], wv, accB);
            }
            h1s[0][lane] = fmaxf(accA, 0.f);
            h1s[1][lane] = fmaxf(accB, 0.f);
        }
        LDS_SYNC();
        if (lane < H) {
            float accA = b2[lane], accB = b2[lane];
            #pragma unroll
            for (int j = 0; j < 16; ++j) {
                float wv = W2[lane * 16 + j];
                accA = fmaf(h1s[0][j], wv, accA);
                accB = fmaf(h1s[1][j], wv, accB);
            }
            out[(size_t)rowA * H + lane] = accA;
            out[(size_t)rowB * H + lane] = accB;
        }
    }
}

extern "C" void kernel_launch(void* const* d_in, const int* in_sizes, int n_in,
                              void* d_out, int out_size, void* d_ws, size_t ws_size,
                              hipStream_t stream)
{
    const float* x    = (const float*)d_in[0];
    const float* Wih1 = (const float*)d_in[1];
    const float* Whh1 = (const float*)d_in[2];
    const float* bih1 = (const float*)d_in[3];
    const float* bhh1 = (const float*)d_in[4];
    const float* Wih2 = (const float*)d_in[5];
    const float* Whh2 = (const float*)d_in[6];
    const float* bih2 = (const float*)d_in[7];
    const float* bhh2 = (const float*)d_in[8];
    const float* W1   = (const float*)d_in[9];
    const float* b1   = (const float*)d_in[10];
    const float* W2   = (const float*)d_in[11];
    const float* b2   = (const float*)d_in[12];
    float* out = (float*)d_out;

    const int B = in_sizes[0] / (T * P);             // 4096
    hipLaunchKernelGGL(lstm2_split5, dim3(B / 2), dim3(128), 0, stream,
                       x, Wih1, Whh1, bih1, bhh1, Wih2, Whh2, bih2, bhh2,
                       W1, b1, W2, b2, out);
}

// Round 13
// 405.044 us; speedup vs baseline: 1.2585x; 1.2585x over previous
//
#include <hip/hip_runtime.h>

constexpr int T = 168;
constexpr int P = 16;
constexpr int H = 24;

typedef float v2f __attribute__((ext_vector_type(2)));

__device__ __forceinline__ v2f mk2(float a, float b) { v2f r; r[0] = a; r[1] = b; return r; }
__device__ __forceinline__ v2f bc2(float a)          { v2f r; r[0] = a; r[1] = a; return r; }
// 2 fp32 FMAs in one instruction (v_pk_fma_f32).
__device__ __forceinline__ v2f pkfma(v2f a, v2f b, v2f c) {
    return __builtin_elementwise_fma(a, b, c);
}

__device__ __forceinline__ float rcp_f(float x) { return __builtin_amdgcn_rcpf(x); }
__device__ __forceinline__ float sigm_f(float x) { return rcp_f(1.f + __expf(-x)); }
// tanh(x) = 2*sigmoid(2x) - 1
__device__ __forceinline__ float tanh_fast(float x) {
    return fmaf(2.f, rcp_f(1.f + __expf(-2.f * x)), -1.f);
}

#define KEEP2(v) asm volatile("" : "+v"(v))
// Intra-wave LDS write->read ordering + compiler reorder fence.
#define LDS_SYNC() asm volatile("s_waitcnt lgkmcnt(0)" ::: "memory")

// 4 packed FMAs: acc += v4.{x,y,z,w} * w[b..b+3]
#define PK4(acc_, v4_, w_, b_) do {                       \
    acc_ = pkfma(bc2((v4_).x), (w_)[(b_)],     acc_);     \
    acc_ = pkfma(bc2((v4_).y), (w_)[(b_) + 1], acc_);     \
    acc_ = pkfma(bc2((v4_).z), (w_)[(b_) + 2], acc_);     \
    acc_ = pkfma(bc2((v4_).w), (w_)[(b_) + 3], acc_); } while (0)

// Gate nonlinearity + state update + h store. tdst==nullptr folds away.
__device__ __forceinline__ void act_store(v2f g, int lane, int half,
                                          float& c, float* hdst, float* tdst)
{
    float a0 = sigm_f(g[0]);                        // i (half0) | f (half1)
    float px = (half == 0) ? g[1] + g[1] : g[1];
    float sv = sigm_f(px);
    float a1 = (half == 0) ? sv + sv - 1.f : sv;    // tanh(g) | o
    float fa = __shfl(a0, lane + 24);
    float oa = __shfl(a1, lane + 24);
    c = fmaf(fa, c, a0 * a1);
    float hv = oa * tanh_fast(c);
    if (tdst) {
        float th = tanh_fast(hv);
        if (lane < H) { hdst[lane] = hv; tdst[lane] = th; }
    } else {
        if (lane < H) hdst[lane] = hv;
    }
}

// One L1 timestep, x read from the LDS stage buffer (broadcast ds_read_b128).
#define L1_STEP_L(xlsrow_, hrow_, c_, tdst_) do {                      \
    v2f g_ = bias;                                                     \
    _Pragma("unroll")                                                  \
    for (int j_ = 0; j_ < P / 4; ++j_) {                               \
        float4 v_ = ((const float4*)(xlsrow_))[j_];                    \
        PK4(g_, v_, w, 4 * j_);                                        \
    }                                                                  \
    _Pragma("unroll")                                                  \
    for (int k_ = 0; k_ < H / 4; ++k_) {                               \
        float4 hv_ = ((const float4*)(hrow_))[k_];                     \
        PK4(g_, hv_, w, H + 4 * k_);                                   \
    }                                                                  \
    act_store(g_, lane, half, c_, hrow_, tdst_);                       \
} while (0)

// One L2 timestep for one row: f = bias + Wih2*t1 + Whh2*h2; update c,h.
#define L2_STEP(trow_, hrow_, c_) do {                                 \
    v2f f_ = bias;                                                     \
    _Pragma("unroll")                                                  \
    for (int k_ = 0; k_ < H / 4; ++k_) {                               \
        float4 tv_ = ((const float4*)(trow_))[k_];                     \
        PK4(f_, tv_, w, 4 * k_);                                       \
    }                                                                  \
    _Pragma("unroll")                                                  \
    for (int k_ = 0; k_ < H / 4; ++k_) {                               \
        float4 hv_ = ((const float4*)(hrow_))[k_];                     \
        PK4(f_, hv_, w, H + 4 * k_);                                   \
    }                                                                  \
    act_store(f_, lane, half, c_, hrow_, nullptr);                     \
} while (0)

// R17: hide x HBM latency with an LDS prefetch pipeline (on the proven R15
// base, 335us steady). Evidence chain: R15 wave-superstep = ~9600cy with only
// ~1500cy issue content; LDS (~120cy) and act chains (~150cy) are 10x too
// small to explain the ~8000cy stall. x is streamed exactly once (FETCH =
// 43MB = |x|), so wave0's per-step 64B/row x loads are HBM misses (~900+cy,
// worse under 2048-wave queueing) sitting at the top of each sub-step on the
// recurrent path. R16 hid them by hoisting FMAs but paid ~40 regs and fell
// off the 128-reg/4-wave tier (occ 36->17%, LOSS). This costs ~8 regs:
//   - x staged in chunks of 8 timesteps: xls[2][row][8][16] (4KB, wave0-only)
//   - per chunk: 1 coalesced global_load_dwordx4 per lane (all 64 lanes:
//     lanes 0-31 row A, 32-63 row B) issued 4 supersteps EARLY into a held
//     float4; ds_write + LDS_SYNC at the superstep that first uses the chunk
//   - XPART reads x via broadcast ds_read_b128 (conflict-free), like HPART
// No cross-wave sync added (buffer is wave0-private); wave1 untouched.
// Keeps: R15 superstep structure (2 steps/superstep, 84 barriers), wave0=L1/
// wave1=L2 split, t1 double-buffer, uniform init, amdgpu_num_vgpr(128),
// 2048 blocks x 2 waves = 4 waves/SIMD.
__global__ __attribute__((amdgpu_flat_work_group_size(128, 128),
                          amdgpu_num_vgpr(128)))
void lstm2_split6(const float* __restrict__ x,
                  const float* __restrict__ Wih1, const float* __restrict__ Whh1,
                  const float* __restrict__ bih1, const float* __restrict__ bhh1,
                  const float* __restrict__ Wih2, const float* __restrict__ Whh2,
                  const float* __restrict__ bih2, const float* __restrict__ bhh2,
                  const float* __restrict__ W1, const float* __restrict__ b1,
                  const float* __restrict__ W2, const float* __restrict__ b2,
                  float* __restrict__ out)
{
    const int tid  = threadIdx.x;
    const int wid  = tid >> 6;                    // 0: L1 wave, 1: L2 wave
    const int lane = tid & 63;
    const int s    = (lane < 48) ? lane : 47;     // clamp idle lanes
    const int u    = s % H;                       // unit 0..23
    const int half = s / H;                       // 0: {i,g}, 1: {f,o}
    const int q0   = half * H + u;                // i or f gate row
    const int q1   = (2 + half) * H + u;          // g or o gate row
    const int rowA = blockIdx.x * 2;
    const int rowB = rowA + 1;

    // ---- uniform weight init: 48 v2f = 96 regs, same mapping both waves ----
    // w[0..23]:  input-weight pairs {q0,q1} (cols >= nin zero-padded)
    // w[24..47]: recurrent pairs {q0,q1}
    const float* __restrict__ Wi = wid ? Wih2 : Wih1;
    const float* __restrict__ Wh = wid ? Whh2 : Whh1;
    const float* __restrict__ bi = wid ? bih2 : bih1;
    const float* __restrict__ bh = wid ? bhh2 : bhh1;
    const int nin = wid ? H : P;                  // 24 | 16 (wave-uniform)

    v2f w[48];
    #pragma unroll
    for (int k = 0; k < H; ++k)
        w[k] = (k < nin) ? mk2(Wi[q0 * nin + k], Wi[q1 * nin + k]) : bc2(0.f);
    #pragma unroll
    for (int k = 0; k < H; ++k)
        w[H + k] = mk2(Wh[q0 * H + k], Wh[q1 * H + k]);
    v2f bias = mk2(bi[q0] + bh[q0], bi[q1] + bh[q1]);

    #pragma unroll
    for (int k = 0; k < 48; ++k) KEEP2(w[k]);
    KEEP2(bias);

    __shared__ __align__(16) float h1s[2][32];          // L1 h (wave0-private)
    __shared__ __align__(16) float t1s[2][2][2][32];    // [buf][step][row]
    __shared__ __align__(16) float h2s[2][32];          // L2 h (wave1-private)
    __shared__ __align__(16) float xls[2][2][8][16];    // [buf][row][step][col]

    const float* __restrict__ xA = x + (size_t)rowA * T * P;  // wave-uniform
    const float* __restrict__ xB = x + (size_t)rowB * T * P;

    float cA = 0.f, cB = 0.f;     // c1 (wave0) / c2 (wave1)

    // x-stage lane mapping (wave0): lanes 0-31 row A, lanes 32-63 row B;
    // each lane owns one float4 of the 512B per-row chunk.
    const int xr  = lane >> 5;
    const int xo4 = lane & 31;
    const float* __restrict__ xbase = xr ? xB : xA;
    float4 xst;                                    // in-flight chunk staging

    // ---- superstep 0: wave0 = L1 steps {0,1}; wave1 zero-inits h2 ----
    if (wid == 0) {
        // stage chunk 0 (steps 0..7): latency exposed once, here only
        xst = ((const float4*)xbase)[xo4];
        ((float4*)xls[0][xr])[xo4] = xst;          // waits vmcnt via use
        xst = ((const float4*)(xbase + 128))[xo4]; // chunk 1 in flight
        LDS_SYNC();                                // chunk 0 visible to us

        // step 0: h1 = 0 -> x-part only
        {
            v2f g = bias;
            #pragma unroll
            for (int j = 0; j < P / 4; ++j) {
                float4 v = ((const float4*)xls[0][0][0])[j];
                PK4(g, v, w, 4 * j);
            }
            act_store(g, lane, half, cA, h1s[0], t1s[0][0][0]);
        }
        {
            v2f g = bias;
            #pragma unroll
            for (int j = 0; j < P / 4; ++j) {
                float4 v = ((const float4*)xls[0][1][0])[j];
                PK4(g, v, w, 4 * j);
            }
            act_store(g, lane, half, cB, h1s[1], t1s[0][0][1]);
        }
        LDS_SYNC();                     // own h1 writes -> own reads
        // step 1: full
        L1_STEP_L(xls[0][0][1], h1s[0], cA, t1s[0][1][0]);
        L1_STEP_L(xls[0][1][1], h1s[1], cB, t1s[0][1][1]);
    } else {
        if (lane < H) { h2s[0][lane] = 0.f; h2s[1][lane] = 0.f; }
    }
    LDS_SYNC();
    __builtin_amdgcn_s_barrier();

    // ---- supersteps 1..83: wave0 = L1 {2s,2s+1}; wave1 = L2 {2s-2,2s-1} ----
    for (int ss = 1; ss < T / 2; ++ss) {
        if (wid == 0) {
            // chunk rotation: superstep ss uses chunk ss>>2 (8 steps/chunk)
            if ((ss & 3) == 0) {
                const int ci = ss >> 2;            // 1..20
                ((float4*)xls[ci & 1][xr])[xo4] = xst;   // waits vmcnt
                if (ci < 20)
                    xst = ((const float4*)(xbase + (ci + 1) * 128))[xo4];
                LDS_SYNC();                        // chunk ci visible
            }
            const int xb = (ss >> 2) & 1;
            const int ta = 2 * ss;
            L1_STEP_L(xls[xb][0][ta & 7],       h1s[0], cA, t1s[ss & 1][0][0]);
            L1_STEP_L(xls[xb][1][ta & 7],       h1s[1], cB, t1s[ss & 1][0][1]);
            LDS_SYNC();
            L1_STEP_L(xls[xb][0][(ta + 1) & 7], h1s[0], cA, t1s[ss & 1][1][0]);
            L1_STEP_L(xls[xb][1][(ta + 1) & 7], h1s[1], cB, t1s[ss & 1][1][1]);
        } else {
            const int pb = (ss - 1) & 1;
            L2_STEP(t1s[pb][0][0], h2s[0], cA);
            L2_STEP(t1s[pb][0][1], h2s[1], cB);
            LDS_SYNC();
            L2_STEP(t1s[pb][1][0], h2s[0], cA);
            L2_STEP(t1s[pb][1][1], h2s[1], cB);
        }
        LDS_SYNC();
        __builtin_amdgcn_s_barrier();
    }

    // ---- tail (wave1 only): L2 steps {166,167} from buf 1, then head ----
    if (wid == 1) {
        L2_STEP(t1s[1][0][0], h2s[0], cA);
        L2_STEP(t1s[1][0][1], h2s[1], cB);
        LDS_SYNC();
        L2_STEP(t1s[1][1][0], h2s[0], cA);
        L2_STEP(t1s[1][1][1], h2s[1], cB);
        LDS_SYNC();

        // head: tanh -> fc1(16, relu) -> fc2(24), both rows (intra-wave)
        if (lane < H) {
            t1s[0][0][0][lane] = tanh_fast(h2s[0][lane]);
            t1s[0][0][1][lane] = tanh_fast(h2s[1][lane]);
        }
        LDS_SYNC();
        if (lane < 16) {
            float accA = b1[lane], accB = b1[lane];
            #pragma unroll
            for (int j = 0; j < H; ++j) {
                float wv = W1[lane * H + j];
                accA = fmaf(t1s[0][0][0][j], wv, accA);
                accB = fmaf(t1s[0][0][1][j], wv, accB);
            }
            h1s[0][lane] = fmaxf(accA, 0.f);
            h1s[1][lane] = fmaxf(accB, 0.f);
        }
        LDS_SYNC();
        if (lane < H) {
            float accA = b2[lane], accB = b2[lane];
            #pragma unroll
            for (int j = 0; j < 16; ++j) {
                float wv = W2[lane * 16 + j];
                accA = fmaf(h1s[0][j], wv, accA);
                accB = fmaf(h1s[1][j], wv, accB);
            }
            out[(size_t)rowA * H + lane] = accA;
            out[(size_t)rowB * H + lane] = accB;
        }
    }
}

extern "C" void kernel_launch(void* const* d_in, const int* in_sizes, int n_in,
                              void* d_out, int out_size, void* d_ws, size_t ws_size,
                              hipStream_t stream)
{
    const float* x    = (const float*)d_in[0];
    const float* Wih1 = (const float*)d_in[1];
    const float* Whh1 = (const float*)d_in[2];
    const float* bih1 = (const float*)d_in[3];
    const float* bhh1 = (const float*)d_in[4];
    const float* Wih2 = (const float*)d_in[5];
    const float* Whh2 = (const float*)d_in[6];
    const float* bih2 = (const float*)d_in[7];
    const float* bhh2 = (const float*)d_in[8];
    const float* W1   = (const float*)d_in[9];
    const float* b1   = (const float*)d_in[10];
    const float* W2   = (const float*)d_in[11];
    const float* b2   = (const float*)d_in[12];
    float* out = (float*)d_out;

    const int B = in_sizes[0] / (T * P);             // 4096
    hipLaunchKernelGGL(lstm2_split6, dim3(B / 2), dim3(128), 0, stream,
                       x, Wih1, Whh1, bih1, bhh1, Wih2, Whh2, bih2, bhh2,
                       W1, b1, W2, b2, out);
}